// Round 5
// baseline (308.953 us; speedup 1.0000x reference)
//
#include <hip/hip_runtime.h>
#include <hip/hip_bf16.h>

// DecoderCell: attention (2-layer tanh MLP + softmax over L) + context + LSTM cell.
// Dims: L=512, B=256, Q=512, IN=512, H=1024, A=512, 4H=4096.
// R5 changes vs R4 (attgemm occupancy round):
//  - attgemm: col-chunked (2 x 32 cols/wave) -> acc[4][2]+bF[2] halves K-loop VGPR;
//    __launch_bounds__(512,4) targets <=128 VGPR -> 4 waves/SIMD -> 2 blocks/CU
//    (was ~150 VGPR -> 1 block/CU, no stage/compute overlap).
//  - everything else identical to R4.

typedef short bf16x8 __attribute__((ext_vector_type(8)));   // 8 bf16 = 4 VGPR
typedef float f32x4 __attribute__((ext_vector_type(4)));
typedef unsigned short u16x4 __attribute__((ext_vector_type(4)));

__device__ __forceinline__ unsigned short f2bf(float f) {   // RNE f32->bf16
  unsigned int u = __builtin_bit_cast(unsigned int, f);
  u += 0x7fffu + ((u >> 16) & 1u);
  return (unsigned short)(u >> 16);
}
__device__ __forceinline__ float bf2f(unsigned short u) {
  unsigned int x = (unsigned int)u << 16;
  return __builtin_bit_cast(float, x);
}
__device__ __forceinline__ float fast_tanh(float x) {
  float e = __expf(2.0f * x);          // overflow -> inf -> tanh -> 1 (safe form)
  return 1.0f - 2.0f / (e + 1.0f);
}
__device__ __forceinline__ float fast_sig(float x) {
  return 1.0f / (1.0f + __expf(-x));
}
__device__ __forceinline__ f32x4 mfma16(bf16x8 a, bf16x8 b, f32x4 c) {
  return __builtin_amdgcn_mfma_f32_16x16x32_bf16(a, b, c, 0, 0, 0);
}

// ---------------- prep: (blocks 0..127) att1_w query-part -> bf16 B-frags
//                  (blocks 128..383) base partials h0 @ att1_w[:, :1024].T ----------------
__global__ void k_prep(const float* __restrict__ a1w, const float* __restrict__ h0,
                       unsigned short* __restrict__ wqf, float* __restrict__ part1) {
  __shared__ float sh[4096], swt[4096];
  int bx = blockIdx.x;
  if (bx < 128) {                               // ---- wqf role ----
    int g = bx * 256 + threadIdx.x;             // 512 frags * 64 lanes = 32768
    int lane = g & 63, frag = g >> 6;
    int ab = frag >> 4, ksf = frag & 15;
    int a = ab * 16 + (lane & 15);
    int k = ksf * 32 + (lane >> 4) * 8;
    const float* src = a1w + (size_t)a * 1536 + 1024 + k;
    float4 v0 = *reinterpret_cast<const float4*>(src);
    float4 v1 = *reinterpret_cast<const float4*>(src + 4);
    unsigned short* dst = wqf + ((size_t)frag * 64 + lane) * 8;
    *(u16x4*)dst       = u16x4{ f2bf(v0.x), f2bf(v0.y), f2bf(v0.z), f2bf(v0.w) };
    *(u16x4*)(dst + 4) = u16x4{ f2bf(v1.x), f2bf(v1.y), f2bf(v1.z), f2bf(v1.w) };
    return;
  }
  // ---- base1 role: tile 64x64, split-K 8 ----
  int blk = bx - 128;                           // 256 = 8 ksp * 4 bt * 8 at
  int at = blk & 7, bt = (blk >> 3) & 3, ksp = blk >> 5;
  int a0 = at * 64, b0 = bt * 64, kbase = ksp * 128;
  int t = threadIdx.x;
  int ta = t & 15, tb = t >> 4;
  float acc[4][4] = {};
  for (int half = 0; half < 2; half++) {
    int k0 = kbase + half * 64;
    for (int i = 0; i < 4; i++) {
      int u = i * 256 + t;
      int row = u >> 4, c4 = (u & 15) << 2;
      float4 vh = *reinterpret_cast<const float4*>(h0 + (size_t)(b0 + row) * 1024 + k0 + c4);
      float4 vw = *reinterpret_cast<const float4*>(a1w + (size_t)(a0 + row) * 1536 + k0 + c4);
      int off = (row * 256 + c4 * 4) ^ ((row & 7) << 4);
      *(float4*)((char*)sh + off) = vh;
      *(float4*)((char*)swt + off) = vw;
    }
    __syncthreads();
    for (int k4 = 0; k4 < 16; k4++) {
      float4 hv[4], wv[4];
#pragma unroll
      for (int i = 0; i < 4; i++) {
        int rh = tb + 16 * i;
        hv[i] = *(const float4*)((char*)sh + ((rh * 256 + k4 * 16) ^ ((rh & 7) << 4)));
        int ra = ta + 16 * i;
        wv[i] = *(const float4*)((char*)swt + ((ra * 256 + k4 * 16) ^ ((ra & 7) << 4)));
      }
#pragma unroll
      for (int i = 0; i < 4; i++)
#pragma unroll
        for (int j = 0; j < 4; j++)
          acc[i][j] += hv[i].x * wv[j].x + hv[i].y * wv[j].y +
                       hv[i].z * wv[j].z + hv[i].w * wv[j].w;
    }
    __syncthreads();
  }
  float* dst = part1 + (size_t)ksp * 131072;
#pragma unroll
  for (int i = 0; i < 4; i++)
#pragma unroll
    for (int j = 0; j < 4; j++)
      dst[(size_t)(b0 + tb + 16 * i) * 512 + a0 + ta + 16 * j] = acc[i][j];
}

__global__ void k_base2(const float* __restrict__ part1, const float* __restrict__ a1b,
                        float* __restrict__ base) {
  int idx = blockIdx.x * 256 + threadIdx.x;     // 131072
  float s = a1b[idx & 511];
  for (int ks = 0; ks < 8; ks++) s += part1[(size_t)ks * 131072 + idx];
  base[idx] = s;
}

// ---------------- fused attgemm: GEMM + tanh/att2 + exp + weighted-qd partial --------------
// Grid: 512 = 16 bt (inner) x 32 lt. Block: 16 b x 16 l, 512 thr / 8 waves.
// Loop ls<4: stage qd[4l x 16b][512] f32->bf16 LDS (64KB, XOR swz); wave w does cols
// {chunk*256 + w*32 .. +32} for chunk<2 (acc[4][2] keeps VGPR <=128 -> 2 blocks/CU);
// epilogue tanh*w2 -> cross-wave reduce -> araw -> e=exp*mask -> num += e*qd(LDS), den += e.
__global__ __launch_bounds__(512, 4) void k_attgemm(
    const float* __restrict__ qd, const unsigned short* __restrict__ wqf,
    const float* __restrict__ base, const float* __restrict__ w2,
    const float* __restrict__ mask, float* __restrict__ nump,
    float* __restrict__ denp) {
  extern __shared__ char smem[];                 // 64K A-tile | 2K sRed | 256B e_lds
  float* sRed = (float*)(smem + 65536);
  float* e_lds = (float*)(smem + 65536 + 2048);
  int t = threadIdx.x;
  int bt = blockIdx.x & 15, lt = blockIdx.x >> 4;
  int b0 = bt * 16, l0 = lt * 16;
  int lane = t & 63, lr = lane & 15, lh = lane >> 4;
  int w = t >> 6;
  int b_own = t >> 5, q0 = (t & 31) * 16;        // ctx-accum ownership
  float ctx_acc[16] = {};
  float den_acc = 0.0f;
  for (int ls = 0; ls < 4; ls++) {
    int l_base = l0 + ls * 4;
    for (int i = 0; i < 16; i++) {               // stage 64 rows x 512 cols f32->bf16
      int u = i * 512 + t;
      int row = u >> 7, c4 = (u & 127) << 2;
      float4 v = *reinterpret_cast<const float4*>(
          qd + ((size_t)(l_base + (row >> 4)) * 256 + b0 + (row & 15)) * 512 + c4);
      int loff = (row * 1024 + c4 * 2) ^ ((row & 7) << 4);
      *(u16x4*)(smem + loff) = u16x4{ f2bf(v.x), f2bf(v.y), f2bf(v.z), f2bf(v.w) };
    }
    __syncthreads();
    float rs[4][4] = {};                         // [mi][r], accumulates across chunks
#pragma unroll
    for (int chunk = 0; chunk < 2; chunk++) {
      f32x4 acc[4][2] = {};                      // [mi][ni]
#pragma unroll 4
      for (int ks = 0; ks < 16; ks++) {
        bf16x8 aF[4], bF[2];
#pragma unroll
        for (int mi = 0; mi < 4; mi++) {
          int row = mi * 16 + lr;
          int off = (row * 1024 + (ks * 32 + lh * 8) * 2) ^ ((row & 7) << 4);
          aF[mi] = *(const bf16x8*)(smem + off);
        }
#pragma unroll
        for (int ni = 0; ni < 2; ni++) {
          int ab = chunk * 16 + w * 2 + ni;
          bF[ni] = *(const bf16x8*)(wqf + ((size_t)(ab * 16 + ks) * 64 + lane) * 8);
        }
#pragma unroll
        for (int mi = 0; mi < 4; mi++)
#pragma unroll
          for (int ni = 0; ni < 2; ni++)
            acc[mi][ni] = mfma16(aF[mi], bF[ni], acc[mi][ni]);
      }
      // epilogue: +base, tanh, dot att2_w over this wave's 32 cols
#pragma unroll
      for (int ni = 0; ni < 2; ni++) {
        int a = chunk * 256 + w * 32 + ni * 16 + lr;
        float w2v = w2[a];
#pragma unroll
        for (int mi = 0; mi < 4; mi++)
#pragma unroll
          for (int r = 0; r < 4; r++) {
            int b = b0 + lh * 4 + r;             // (row&15) == lh*4+r
            float val = acc[mi][ni][r] + base[(size_t)b * 512 + a];
            rs[mi][r] += fast_tanh(val) * w2v;
          }
      }
    }
#pragma unroll
    for (int mi = 0; mi < 4; mi++)
#pragma unroll
      for (int r = 0; r < 4; r++) {
        float v = rs[mi][r];
        v += __shfl_xor(v, 1); v += __shfl_xor(v, 2);
        v += __shfl_xor(v, 4); v += __shfl_xor(v, 8);
        rs[mi][r] = v;
      }
    if (lr == 0)
#pragma unroll
      for (int mi = 0; mi < 4; mi++)
#pragma unroll
        for (int r = 0; r < 4; r++)
          sRed[w * 64 + mi * 16 + lh * 4 + r] = rs[mi][r];
    __syncthreads();
    if (t < 64) {                                // araw -> e (exp-no-max, *mask)
      float araw = 0.0f;
#pragma unroll
      for (int j = 0; j < 8; j++) araw += sRed[j * 64 + t];
      int l = l_base + (t >> 4), b = b0 + (t & 15);
      e_lds[t] = __expf(araw) * mask[(size_t)l * 256 + b];
    }
    __syncthreads();
    // ctx accumulation: thread owns (b_own, q0..q0+15); rows li*16+b_own, li<4
#pragma unroll
    for (int li = 0; li < 4; li++) {
      int row = li * 16 + b_own;
      float e = e_lds[row];
      if ((t & 31) == 0) den_acc += e;
      int sw = (row & 7) << 4;
      bf16x8 v0 = *(const bf16x8*)(smem + ((row * 1024 + q0 * 2) ^ sw));
      bf16x8 v1 = *(const bf16x8*)(smem + ((row * 1024 + q0 * 2 + 16) ^ sw));
#pragma unroll
      for (int j = 0; j < 8; j++) {
        ctx_acc[j]     += e * bf2f((unsigned short)v0[j]);
        ctx_acc[8 + j] += e * bf2f((unsigned short)v1[j]);
      }
    }
    __syncthreads();                             // LDS reads done -> safe to restage
  }
  float* dst = nump + ((size_t)lt * 256 + b0 + b_own) * 512 + q0;
#pragma unroll
  for (int j = 0; j < 4; j++)
    *reinterpret_cast<float4*>(dst + j * 4) =
        float4{ ctx_acc[j * 4], ctx_acc[j * 4 + 1], ctx_acc[j * 4 + 2], ctx_acc[j * 4 + 3] };
  if ((t & 31) == 0) denp[lt * 256 + b0 + b_own] = den_acc;
}

// ---------------- ctx reduction: ctx[b][q] = sum_lt num / sum_lt den ----------------
__global__ void k_ctxred(const float* __restrict__ nump, const float* __restrict__ denp,
                         float* __restrict__ outF) {
  int idx = blockIdx.x * 256 + threadIdx.x;      // 131072
  int b = idx >> 9;
  float s = 0.0f, d = 0.0f;
#pragma unroll 8
  for (int lt = 0; lt < 32; lt++) {
    s += nump[(size_t)lt * 131072 + idx];
    d += denp[lt * 256 + b];
  }
  outF[idx] = s / d;                             // ctx at d_out offset 0
}

// ---------------- build x = [input|ctx|h_parent|h0] in bf16 MFMA A-fragment order --------
__global__ void k_xf(const float* __restrict__ inp, const float* __restrict__ ctx,
                     const float* __restrict__ hist, const int* __restrict__ pidx,
                     const float* __restrict__ h0, unsigned short* __restrict__ xf) {
  int g = blockIdx.x * 256 + threadIdx.x;        // 1536 frags * 64 lanes = 98304
  int lane = g & 63, frag = g >> 6;
  int mb = frag / 96, kstep = frag % 96;
  int b = mb * 16 + (lane & 15);
  int k = kstep * 32 + (lane >> 4) * 8;
  const float* src;
  if (k < 512)       src = inp  + (size_t)b * 512 + k;
  else if (k < 1024) src = ctx  + (size_t)b * 512 + (k - 512);
  else if (k < 2048) src = hist + ((size_t)pidx[b] * 256 + b) * 1024 + (k - 1024);
  else               src = h0   + (size_t)b * 1024 + (k - 2048);
  float4 v0 = *reinterpret_cast<const float4*>(src);
  float4 v1 = *reinterpret_cast<const float4*>(src + 4);
  unsigned short* dst = xf + ((size_t)frag * 64 + lane) * 8;
  *(u16x4*)dst       = u16x4{ f2bf(v0.x), f2bf(v0.y), f2bf(v0.z), f2bf(v0.w) };
  *(u16x4*)(dst + 4) = u16x4{ f2bf(v1.x), f2bf(v1.y), f2bf(v1.z), f2bf(v1.w) };
}

// ---------------- gates GEMM: (256 x 3072) x (4096 x 3072)^T, 128 nt x 4 ksp -------------
__global__ __launch_bounds__(256, 4) void k_gates(
    const unsigned short* __restrict__ xf, const float* __restrict__ Wih,
    const float* __restrict__ Whh, float* __restrict__ part) {
  int blk = blockIdx.x;                          // 512 = 128 nt * 4 ksp
  int nt = blk & 127, ksp = blk >> 7;
  int n0 = nt * 32, kbeg = ksp * 768;
  int t = threadIdx.x;
  int lane = t & 63, lr = lane & 15, lh = lane >> 4;
  int w = t >> 6;                                // wave covers b-range w*64
  f32x4 acc[4][2] = {};
#pragma unroll 2
  for (int ks = 0; ks < 24; ks++) {
    int k0 = kbeg + ks * 32;
    int kstep = k0 >> 5;
    bf16x8 aF[4], bF[2];
#pragma unroll
    for (int mi = 0; mi < 4; mi++) {
      int mb = w * 4 + mi;
      aF[mi] = *(const bf16x8*)(xf + ((size_t)(mb * 96 + kstep) * 64 + lane) * 8);
    }
    const float* Wp; int ldw, kk;
    if (k0 < 2048) { Wp = Wih; ldw = 2048; kk = k0; }
    else           { Wp = Whh; ldw = 1024; kk = k0 - 2048; }
#pragma unroll
    for (int ni = 0; ni < 2; ni++) {
      int j = n0 + ni * 16 + lr;
      const float* src = Wp + (size_t)j * ldw + kk + lh * 8;
      float4 v0 = *reinterpret_cast<const float4*>(src);
      float4 v1 = *reinterpret_cast<const float4*>(src + 4);
      bf16x8 bv;
      bv[0] = (short)f2bf(v0.x); bv[1] = (short)f2bf(v0.y);
      bv[2] = (short)f2bf(v0.z); bv[3] = (short)f2bf(v0.w);
      bv[4] = (short)f2bf(v1.x); bv[5] = (short)f2bf(v1.y);
      bv[6] = (short)f2bf(v1.z); bv[7] = (short)f2bf(v1.w);
      bF[ni] = bv;
    }
#pragma unroll
    for (int mi = 0; mi < 4; mi++)
#pragma unroll
      for (int ni = 0; ni < 2; ni++)
        acc[mi][ni] = mfma16(aF[mi], bF[ni], acc[mi][ni]);
  }
  float* dst = part + (size_t)ksp * (256 * 4096);
#pragma unroll
  for (int mi = 0; mi < 4; mi++)
#pragma unroll
    for (int ni = 0; ni < 2; ni++)
#pragma unroll
      for (int r = 0; r < 4; r++) {
        int b = w * 64 + mi * 16 + lh * 4 + r;
        int j = n0 + ni * 16 + lr;
        dst[(size_t)b * 4096 + j] = acc[mi][ni][r];
      }
}

// ---------------- LSTM pointwise: reduce 4 split-K partials + gates + outputs -------------
__global__ void k_lstm(const float* __restrict__ part, const float* __restrict__ bih,
                       const float* __restrict__ bhh, const float* __restrict__ c0,
                       float* __restrict__ out) {
  int idx = blockIdx.x * 256 + threadIdx.x;      // 262144
  int h = idx & 1023;
  int b = idx >> 10;
  const float* p = part + (size_t)b * 4096;
  float gi = bih[h] + bhh[h];
  float gf = bih[1024 + h] + bhh[1024 + h];
  float gg = bih[2048 + h] + bhh[2048 + h];
  float go = bih[3072 + h] + bhh[3072 + h];
#pragma unroll
  for (int ks = 0; ks < 4; ks++) {
    const float* q = p + (size_t)ks * 1048576;
    gi += q[h]; gf += q[1024 + h]; gg += q[2048 + h]; go += q[3072 + h];
  }
  float c = fast_sig(gf) * c0[idx] + fast_sig(gi) * fast_tanh(gg);
  float hv = fast_sig(go) * fast_tanh(c);
  out[131072 + idx] = hv;                        // h1
  out[393216 + idx] = c;                         // c1
}

extern "C" void kernel_launch(void* const* d_in, const int* in_sizes, int n_in,
                              void* d_out, int out_size, void* d_ws, size_t ws_size,
                              hipStream_t stream) {
  const float* qd    = (const float*)d_in[0];
  const float* qmask = (const float*)d_in[1];
  const float* inp   = (const float*)d_in[2];
  const int*   pidx  = (const int*)d_in[3];
  const float* hist  = (const float*)d_in[4];
  const float* h0    = (const float*)d_in[5];
  const float* c0    = (const float*)d_in[6];
  const float* Wih   = (const float*)d_in[7];
  const float* Whh   = (const float*)d_in[8];
  const float* bih   = (const float*)d_in[9];
  const float* bhh   = (const float*)d_in[10];
  const float* a1w   = (const float*)d_in[11];
  const float* a1b   = (const float*)d_in[12];
  const float* a2w   = (const float*)d_in[13];
  float* outF = (float*)d_out;

  char* ws = (char*)d_ws;
  unsigned short* wqf  = (unsigned short*)(ws);                 // 512 KB
  float*          base = (float*)(ws + 524288);                  // 512 KB
  float*          p1   = (float*)(ws + 1048576);                 // 4 MB
  unsigned short* xf   = (unsigned short*)(ws + 5242880);        // 1.5 MB
  float*          denp = (float*)(ws + 6815744);                 // 32 KB
  float*          nump = (float*)(ws + 8388608);                 // 16 MB
  float*          pg   = (float*)(ws + 25165824);                // 16 MB

  (void)hipFuncSetAttribute((const void*)k_attgemm,
                            hipFuncAttributeMaxDynamicSharedMemorySize, 67840);

  k_prep   <<<384,  256, 0, stream>>>(a1w, h0, wqf, p1);
  k_base2  <<<512,  256, 0, stream>>>(p1, a1b, base);
  k_attgemm<<<512,  512, 67840, stream>>>(qd, wqf, base, a2w, qmask, nump, denp);
  k_ctxred <<<512,  256, 0, stream>>>(nump, denp, outF);
  k_xf     <<<384,  256, 0, stream>>>(inp, outF, hist, pidx, h0, xf);
  k_gates  <<<512,  256, 0, stream>>>(xf, Wih, Whh, pg);
  k_lstm   <<<1024, 256, 0, stream>>>(pg, bih, bhh, c0, outF);
}

// Round 6
// 237.878 us; speedup vs baseline: 1.2988x; 1.2988x over previous
//
#include <hip/hip_runtime.h>
#include <hip/hip_bf16.h>

// DecoderCell: attention (2-layer tanh MLP + softmax over L) + context + LSTM cell.
// Dims: L=512, B=256, Q=512, IN=512, H=1024, A=512, 4H=4096.
// R6 = R4 base (249.6 us known-good) + two changes:
//  - attgemm: double-buffered A staging (2x64KB LDS), issue-early/write-late per
//    4-ks chunk (T14) -> HBM stage overlaps MFMA; one barrier per ls fewer.
//    Keeps (512,2) / acc[4][4] (R5's (512,4)+unroll spilled -> regression).
//  - k_ctxred merged into k_xf (ctx-frag threads reduce nump/denp directly).

typedef short bf16x8 __attribute__((ext_vector_type(8)));   // 8 bf16 = 4 VGPR
typedef float f32x4 __attribute__((ext_vector_type(4)));
typedef unsigned short u16x4 __attribute__((ext_vector_type(4)));

__device__ __forceinline__ unsigned short f2bf(float f) {   // RNE f32->bf16
  unsigned int u = __builtin_bit_cast(unsigned int, f);
  u += 0x7fffu + ((u >> 16) & 1u);
  return (unsigned short)(u >> 16);
}
__device__ __forceinline__ float bf2f(unsigned short u) {
  unsigned int x = (unsigned int)u << 16;
  return __builtin_bit_cast(float, x);
}
__device__ __forceinline__ float fast_tanh(float x) {
  float e = __expf(2.0f * x);          // overflow -> inf -> tanh -> 1 (safe form)
  return 1.0f - 2.0f / (e + 1.0f);
}
__device__ __forceinline__ float fast_sig(float x) {
  return 1.0f / (1.0f + __expf(-x));
}
__device__ __forceinline__ f32x4 mfma16(bf16x8 a, bf16x8 b, f32x4 c) {
  return __builtin_amdgcn_mfma_f32_16x16x32_bf16(a, b, c, 0, 0, 0);
}

// ---------------- prep: (blocks 0..127) att1_w query-part -> bf16 B-frags
//                  (blocks 128..383) base partials h0 @ att1_w[:, :1024].T ----------------
__global__ void k_prep(const float* __restrict__ a1w, const float* __restrict__ h0,
                       unsigned short* __restrict__ wqf, float* __restrict__ part1) {
  __shared__ float sh[4096], swt[4096];
  int bx = blockIdx.x;
  if (bx < 128) {                               // ---- wqf role ----
    int g = bx * 256 + threadIdx.x;             // 512 frags * 64 lanes = 32768
    int lane = g & 63, frag = g >> 6;
    int ab = frag >> 4, ksf = frag & 15;
    int a = ab * 16 + (lane & 15);
    int k = ksf * 32 + (lane >> 4) * 8;
    const float* src = a1w + (size_t)a * 1536 + 1024 + k;
    float4 v0 = *reinterpret_cast<const float4*>(src);
    float4 v1 = *reinterpret_cast<const float4*>(src + 4);
    unsigned short* dst = wqf + ((size_t)frag * 64 + lane) * 8;
    *(u16x4*)dst       = u16x4{ f2bf(v0.x), f2bf(v0.y), f2bf(v0.z), f2bf(v0.w) };
    *(u16x4*)(dst + 4) = u16x4{ f2bf(v1.x), f2bf(v1.y), f2bf(v1.z), f2bf(v1.w) };
    return;
  }
  // ---- base1 role: tile 64x64, split-K 8 ----
  int blk = bx - 128;                           // 256 = 8 ksp * 4 bt * 8 at
  int at = blk & 7, bt = (blk >> 3) & 3, ksp = blk >> 5;
  int a0 = at * 64, b0 = bt * 64, kbase = ksp * 128;
  int t = threadIdx.x;
  int ta = t & 15, tb = t >> 4;
  float acc[4][4] = {};
  for (int half = 0; half < 2; half++) {
    int k0 = kbase + half * 64;
    for (int i = 0; i < 4; i++) {
      int u = i * 256 + t;
      int row = u >> 4, c4 = (u & 15) << 2;
      float4 vh = *reinterpret_cast<const float4*>(h0 + (size_t)(b0 + row) * 1024 + k0 + c4);
      float4 vw = *reinterpret_cast<const float4*>(a1w + (size_t)(a0 + row) * 1536 + k0 + c4);
      int off = (row * 256 + c4 * 4) ^ ((row & 7) << 4);
      *(float4*)((char*)sh + off) = vh;
      *(float4*)((char*)swt + off) = vw;
    }
    __syncthreads();
    for (int k4 = 0; k4 < 16; k4++) {
      float4 hv[4], wv[4];
#pragma unroll
      for (int i = 0; i < 4; i++) {
        int rh = tb + 16 * i;
        hv[i] = *(const float4*)((char*)sh + ((rh * 256 + k4 * 16) ^ ((rh & 7) << 4)));
        int ra = ta + 16 * i;
        wv[i] = *(const float4*)((char*)swt + ((ra * 256 + k4 * 16) ^ ((ra & 7) << 4)));
      }
#pragma unroll
      for (int i = 0; i < 4; i++)
#pragma unroll
        for (int j = 0; j < 4; j++)
          acc[i][j] += hv[i].x * wv[j].x + hv[i].y * wv[j].y +
                       hv[i].z * wv[j].z + hv[i].w * wv[j].w;
    }
    __syncthreads();
  }
  float* dst = part1 + (size_t)ksp * 131072;
#pragma unroll
  for (int i = 0; i < 4; i++)
#pragma unroll
    for (int j = 0; j < 4; j++)
      dst[(size_t)(b0 + tb + 16 * i) * 512 + a0 + ta + 16 * j] = acc[i][j];
}

__global__ void k_base2(const float* __restrict__ part1, const float* __restrict__ a1b,
                        float* __restrict__ base) {
  int idx = blockIdx.x * 256 + threadIdx.x;     // 131072
  float s = a1b[idx & 511];
  for (int ks = 0; ks < 8; ks++) s += part1[(size_t)ks * 131072 + idx];
  base[idx] = s;
}

// ---------------- fused attgemm: GEMM + tanh/att2 + exp + weighted-qd partial --------------
// Grid: 512 = 16 bt (inner) x 32 lt. Block: 16 b x 16 l, 512 thr / 8 waves.
// Double-buffered A staging: per 4-ks chunk issue 4 float4 loads for tile ls+1 (sv),
// run 4 ks of MFMAs (latency hiding), then cvt+ds_write into the other LDS buffer.
__global__ __launch_bounds__(512, 2) void k_attgemm(
    const float* __restrict__ qd, const unsigned short* __restrict__ wqf,
    const float* __restrict__ base, const float* __restrict__ w2,
    const float* __restrict__ mask, float* __restrict__ nump,
    float* __restrict__ denp) {
  extern __shared__ char smem[];                 // 2x64K A | 2K sRed | 256B e_lds
  float* sRed = (float*)(smem + 131072);
  float* e_lds = (float*)(smem + 131072 + 2048);
  int t = threadIdx.x;
  int bt = blockIdx.x & 15, lt = blockIdx.x >> 4;
  int b0 = bt * 16, l0 = lt * 16;
  int lane = t & 63, lr = lane & 15, lh = lane >> 4;
  int w = t >> 6;
  int b_own = t >> 5, q0 = (t & 31) * 16;        // ctx-accum ownership
  float ctx_acc[16] = {};
  float den_acc = 0.0f;

  // prologue: stage ls=0 into buffer 0
  for (int i = 0; i < 16; i++) {
    int u = i * 512 + t;
    int row = u >> 7, c4 = (u & 127) << 2;
    float4 v = *reinterpret_cast<const float4*>(
        qd + ((size_t)(l0 + (row >> 4)) * 256 + b0 + (row & 15)) * 512 + c4);
    int loff = (row * 1024 + c4 * 2) ^ ((row & 7) << 4);
    *(u16x4*)(smem + loff) = u16x4{ f2bf(v.x), f2bf(v.y), f2bf(v.z), f2bf(v.w) };
  }
  __syncthreads();

  for (int ls = 0; ls < 4; ls++) {
    char* cb = smem + (size_t)(ls & 1) * 65536;        // compute buffer
    char* nb = smem + (size_t)((ls + 1) & 1) * 65536;  // next-stage buffer
    int lb1 = l0 + (ls + 1) * 4;                       // next tile's l base
    f32x4 acc[4][4] = {};                              // [mi][ni]
    float4 sv[4];
    for (int ks4 = 0; ks4 < 4; ks4++) {
      if (ls < 3) {                                    // issue-early: 4 staging loads
#pragma unroll
        for (int i = 0; i < 4; i++) {
          int u = (ks4 * 4 + i) * 512 + t;
          int row = u >> 7, c4 = (u & 127) << 2;
          sv[i] = *reinterpret_cast<const float4*>(
              qd + ((size_t)(lb1 + (row >> 4)) * 256 + b0 + (row & 15)) * 512 + c4);
        }
      }
#pragma unroll
      for (int ksl = 0; ksl < 4; ksl++) {              // 4 ks of MFMAs hide the loads
        int ks = ks4 * 4 + ksl;
        bf16x8 aF[4], bF[4];
#pragma unroll
        for (int mi = 0; mi < 4; mi++) {
          int row = mi * 16 + lr;
          int off = (row * 1024 + (ks * 32 + lh * 8) * 2) ^ ((row & 7) << 4);
          aF[mi] = *(const bf16x8*)(cb + off);
        }
#pragma unroll
        for (int ni = 0; ni < 4; ni++) {
          int ab = w * 4 + ni;
          bF[ni] = *(const bf16x8*)(wqf + ((size_t)(ab * 16 + ks) * 64 + lane) * 8);
        }
#pragma unroll
        for (int mi = 0; mi < 4; mi++)
#pragma unroll
          for (int ni = 0; ni < 4; ni++)
            acc[mi][ni] = mfma16(aF[mi], bF[ni], acc[mi][ni]);
      }
      if (ls < 3) {                                    // write-late into nb
#pragma unroll
        for (int i = 0; i < 4; i++) {
          int u = (ks4 * 4 + i) * 512 + t;
          int row = u >> 7, c4 = (u & 127) << 2;
          int loff = (row * 1024 + c4 * 2) ^ ((row & 7) << 4);
          *(u16x4*)(nb + loff) =
              u16x4{ f2bf(sv[i].x), f2bf(sv[i].y), f2bf(sv[i].z), f2bf(sv[i].w) };
        }
      }
    }
    // epilogue: +base, tanh, dot att2_w over this wave's 64 cols
    float rs[4][4] = {};
#pragma unroll
    for (int ni = 0; ni < 4; ni++) {
      int a = w * 64 + ni * 16 + lr;
      float w2v = w2[a];
#pragma unroll
      for (int mi = 0; mi < 4; mi++)
#pragma unroll
        for (int r = 0; r < 4; r++) {
          int b = b0 + lh * 4 + r;                     // (row&15) == lh*4+r
          float val = acc[mi][ni][r] + base[(size_t)b * 512 + a];
          rs[mi][r] += fast_tanh(val) * w2v;
        }
    }
#pragma unroll
    for (int mi = 0; mi < 4; mi++)
#pragma unroll
      for (int r = 0; r < 4; r++) {
        float v = rs[mi][r];
        v += __shfl_xor(v, 1); v += __shfl_xor(v, 2);
        v += __shfl_xor(v, 4); v += __shfl_xor(v, 8);
        rs[mi][r] = v;
      }
    if (lr == 0)
#pragma unroll
      for (int mi = 0; mi < 4; mi++)
#pragma unroll
        for (int r = 0; r < 4; r++)
          sRed[w * 64 + mi * 16 + lh * 4 + r] = rs[mi][r];
    __syncthreads();
    if (t < 64) {                                      // araw -> e (exp-no-max, *mask)
      float araw = 0.0f;
#pragma unroll
      for (int j = 0; j < 8; j++) araw += sRed[j * 64 + t];
      int l = l0 + ls * 4 + (t >> 4), b = b0 + (t & 15);
      e_lds[t] = __expf(araw) * mask[(size_t)l * 256 + b];
    }
    __syncthreads();
    // ctx accumulation: thread owns (b_own, q0..q0+15); rows li*16+b_own, li<4
#pragma unroll
    for (int li = 0; li < 4; li++) {
      int row = li * 16 + b_own;
      float e = e_lds[row];
      if ((t & 31) == 0) den_acc += e;
      int sw = (row & 7) << 4;
      bf16x8 v0 = *(const bf16x8*)(cb + ((row * 1024 + q0 * 2) ^ sw));
      bf16x8 v1 = *(const bf16x8*)(cb + ((row * 1024 + q0 * 2 + 16) ^ sw));
#pragma unroll
      for (int j = 0; j < 8; j++) {
        ctx_acc[j]     += e * bf2f((unsigned short)v0[j]);
        ctx_acc[8 + j] += e * bf2f((unsigned short)v1[j]);
      }
    }
    __syncthreads();   // cb reads done (next iter stages into cb); nb writes visible
  }
  float* dst = nump + ((size_t)lt * 256 + b0 + b_own) * 512 + q0;
#pragma unroll
  for (int j = 0; j < 4; j++)
    *reinterpret_cast<float4*>(dst + j * 4) =
        float4{ ctx_acc[j * 4], ctx_acc[j * 4 + 1], ctx_acc[j * 4 + 2], ctx_acc[j * 4 + 3] };
  if ((t & 31) == 0) denp[lt * 256 + b0 + b_own] = den_acc;
}

// ---------------- build x = [input|ctx|h_parent|h0] bf16 A-frags; ctx reduced here -------
__global__ void k_xf(const float* __restrict__ inp, const float* __restrict__ nump,
                     const float* __restrict__ denp, const float* __restrict__ hist,
                     const int* __restrict__ pidx, const float* __restrict__ h0,
                     unsigned short* __restrict__ xf, float* __restrict__ outF) {
  int g = blockIdx.x * 256 + threadIdx.x;        // 1536 frags * 64 lanes = 98304
  int lane = g & 63, frag = g >> 6;
  int mb = frag / 96, kstep = frag % 96;
  int b = mb * 16 + (lane & 15);
  int k = kstep * 32 + (lane >> 4) * 8;
  float4 v0, v1;
  if (k >= 512 && k < 1024) {                    // ctx: reduce 32 partials + den, write out
    int q0 = k - 512;
    float d = 0.0f;
    v0 = float4{0, 0, 0, 0}; v1 = float4{0, 0, 0, 0};
#pragma unroll 4
    for (int lt = 0; lt < 32; lt++) {
      d += denp[lt * 256 + b];
      const float* p = nump + ((size_t)lt * 256 + b) * 512 + q0;
      float4 a0 = *reinterpret_cast<const float4*>(p);
      float4 a1 = *reinterpret_cast<const float4*>(p + 4);
      v0.x += a0.x; v0.y += a0.y; v0.z += a0.z; v0.w += a0.w;
      v1.x += a1.x; v1.y += a1.y; v1.z += a1.z; v1.w += a1.w;
    }
    float inv = 1.0f / d;
    v0.x *= inv; v0.y *= inv; v0.z *= inv; v0.w *= inv;
    v1.x *= inv; v1.y *= inv; v1.z *= inv; v1.w *= inv;
    *reinterpret_cast<float4*>(outF + (size_t)b * 512 + q0) = v0;
    *reinterpret_cast<float4*>(outF + (size_t)b * 512 + q0 + 4) = v1;
  } else {
    const float* src;
    if (k < 512)       src = inp  + (size_t)b * 512 + k;
    else if (k < 2048) src = hist + ((size_t)pidx[b] * 256 + b) * 1024 + (k - 1024);
    else               src = h0   + (size_t)b * 1024 + (k - 2048);
    v0 = *reinterpret_cast<const float4*>(src);
    v1 = *reinterpret_cast<const float4*>(src + 4);
  }
  unsigned short* dst = xf + ((size_t)frag * 64 + lane) * 8;
  *(u16x4*)dst       = u16x4{ f2bf(v0.x), f2bf(v0.y), f2bf(v0.z), f2bf(v0.w) };
  *(u16x4*)(dst + 4) = u16x4{ f2bf(v1.x), f2bf(v1.y), f2bf(v1.z), f2bf(v1.w) };
}

// ---------------- gates GEMM: (256 x 3072) x (4096 x 3072)^T, 128 nt x 4 ksp -------------
__global__ __launch_bounds__(256, 4) void k_gates(
    const unsigned short* __restrict__ xf, const float* __restrict__ Wih,
    const float* __restrict__ Whh, float* __restrict__ part) {
  int blk = blockIdx.x;                          // 512 = 128 nt * 4 ksp
  int nt = blk & 127, ksp = blk >> 7;
  int n0 = nt * 32, kbeg = ksp * 768;
  int t = threadIdx.x;
  int lane = t & 63, lr = lane & 15, lh = lane >> 4;
  int w = t >> 6;                                // wave covers b-range w*64
  f32x4 acc[4][2] = {};
#pragma unroll 2
  for (int ks = 0; ks < 24; ks++) {
    int k0 = kbeg + ks * 32;
    int kstep = k0 >> 5;
    bf16x8 aF[4], bF[2];
#pragma unroll
    for (int mi = 0; mi < 4; mi++) {
      int mb = w * 4 + mi;
      aF[mi] = *(const bf16x8*)(xf + ((size_t)(mb * 96 + kstep) * 64 + lane) * 8);
    }
    const float* Wp; int ldw, kk;
    if (k0 < 2048) { Wp = Wih; ldw = 2048; kk = k0; }
    else           { Wp = Whh; ldw = 1024; kk = k0 - 2048; }
#pragma unroll
    for (int ni = 0; ni < 2; ni++) {
      int j = n0 + ni * 16 + lr;
      const float* src = Wp + (size_t)j * ldw + kk + lh * 8;
      float4 v0 = *reinterpret_cast<const float4*>(src);
      float4 v1 = *reinterpret_cast<const float4*>(src + 4);
      bf16x8 bv;
      bv[0] = (short)f2bf(v0.x); bv[1] = (short)f2bf(v0.y);
      bv[2] = (short)f2bf(v0.z); bv[3] = (short)f2bf(v0.w);
      bv[4] = (short)f2bf(v1.x); bv[5] = (short)f2bf(v1.y);
      bv[6] = (short)f2bf(v1.z); bv[7] = (short)f2bf(v1.w);
      bF[ni] = bv;
    }
#pragma unroll
    for (int mi = 0; mi < 4; mi++)
#pragma unroll
      for (int ni = 0; ni < 2; ni++)
        acc[mi][ni] = mfma16(aF[mi], bF[ni], acc[mi][ni]);
  }
  float* dst = part + (size_t)ksp * (256 * 4096);
#pragma unroll
  for (int mi = 0; mi < 4; mi++)
#pragma unroll
    for (int ni = 0; ni < 2; ni++)
#pragma unroll
      for (int r = 0; r < 4; r++) {
        int b = w * 64 + mi * 16 + lh * 4 + r;
        int j = n0 + ni * 16 + lr;
        dst[(size_t)b * 4096 + j] = acc[mi][ni][r];
      }
}

// ---------------- LSTM pointwise: reduce 4 split-K partials + gates + outputs -------------
__global__ void k_lstm(const float* __restrict__ part, const float* __restrict__ bih,
                       const float* __restrict__ bhh, const float* __restrict__ c0,
                       float* __restrict__ out) {
  int idx = blockIdx.x * 256 + threadIdx.x;      // 262144
  int h = idx & 1023;
  int b = idx >> 10;
  const float* p = part + (size_t)b * 4096;
  float gi = bih[h] + bhh[h];
  float gf = bih[1024 + h] + bhh[1024 + h];
  float gg = bih[2048 + h] + bhh[2048 + h];
  float go = bih[3072 + h] + bhh[3072 + h];
#pragma unroll
  for (int ks = 0; ks < 4; ks++) {
    const float* q = p + (size_t)ks * 1048576;
    gi += q[h]; gf += q[1024 + h]; gg += q[2048 + h]; go += q[3072 + h];
  }
  float c = fast_sig(gf) * c0[idx] + fast_sig(gi) * fast_tanh(gg);
  float hv = fast_sig(go) * fast_tanh(c);
  out[131072 + idx] = hv;                        // h1
  out[393216 + idx] = c;                         // c1
}

extern "C" void kernel_launch(void* const* d_in, const int* in_sizes, int n_in,
                              void* d_out, int out_size, void* d_ws, size_t ws_size,
                              hipStream_t stream) {
  const float* qd    = (const float*)d_in[0];
  const float* qmask = (const float*)d_in[1];
  const float* inp   = (const float*)d_in[2];
  const int*   pidx  = (const int*)d_in[3];
  const float* hist  = (const float*)d_in[4];
  const float* h0    = (const float*)d_in[5];
  const float* c0    = (const float*)d_in[6];
  const float* Wih   = (const float*)d_in[7];
  const float* Whh   = (const float*)d_in[8];
  const float* bih   = (const float*)d_in[9];
  const float* bhh   = (const float*)d_in[10];
  const float* a1w   = (const float*)d_in[11];
  const float* a1b   = (const float*)d_in[12];
  const float* a2w   = (const float*)d_in[13];
  float* outF = (float*)d_out;

  char* ws = (char*)d_ws;
  unsigned short* wqf  = (unsigned short*)(ws);                 // 512 KB
  float*          base = (float*)(ws + 524288);                  // 512 KB
  float*          p1   = (float*)(ws + 1048576);                 // 4 MB
  unsigned short* xf   = (unsigned short*)(ws + 5242880);        // 1.5 MB
  float*          denp = (float*)(ws + 6815744);                 // 32 KB
  float*          nump = (float*)(ws + 8388608);                 // 16 MB
  float*          pg   = (float*)(ws + 25165824);                // 16 MB

  (void)hipFuncSetAttribute((const void*)k_attgemm,
                            hipFuncAttributeMaxDynamicSharedMemorySize, 133376);

  k_prep   <<<384,  256, 0, stream>>>(a1w, h0, wqf, p1);
  k_base2  <<<512,  256, 0, stream>>>(p1, a1b, base);
  k_attgemm<<<512,  512, 133376, stream>>>(qd, wqf, base, a2w, qmask, nump, denp);
  k_xf     <<<384,  256, 0, stream>>>(inp, nump, denp, hist, pidx, h0, xf, outF);
  k_gates  <<<512,  256, 0, stream>>>(xf, Wih, Whh, pg);
  k_lstm   <<<1024, 256, 0, stream>>>(pg, bih, bhh, c0, outF);
}